// Round 4
// baseline (223.683 us; speedup 1.0000x reference)
//
#include <hip/hip_runtime.h>

#define NN 16384
#define DD 256
#define ROW_WORDS 512  // NN/32
#define CAP 224        // per-row neighbor list capacity (deg ~ Poisson(64))
#define LDAP 40        // padded LDS row stride in bf16 elems (80 B)

typedef __attribute__((ext_vector_type(8))) __bf16 bf16x8;
typedef __attribute__((ext_vector_type(4))) float f32x4;

__device__ __forceinline__ unsigned short f2bn(float f) {
    __bf16 h = (__bf16)f;  // compiler emits v_cvt_pk_bf16_f32 for pairs
    return __builtin_bit_cast(unsigned short, h);
}
__device__ __forceinline__ float b2f(unsigned short u) {
    union { unsigned int i; float f; } v; v.i = ((unsigned int)u) << 16; return v.f;
}

// ---------------- fused mid kernel ----------------
// blocks 0..511: GEMM tiles  (out = x@Wu^T + bu + ba ; xab = bf16(x@Wa^T))
// blocks 512.. : edge scatter (bitmap dedup + per-row neighbor lists)
__global__ __launch_bounds__(256) void k_mid(const float* __restrict__ x,
                                             const float* __restrict__ Wu,
                                             const float* __restrict__ bu,
                                             const float* __restrict__ Wa,
                                             const float* __restrict__ ba,
                                             const int* __restrict__ ei,
                                             unsigned int* __restrict__ bm,
                                             unsigned short* __restrict__ list,
                                             int* __restrict__ cnt,
                                             float* __restrict__ out,
                                             unsigned short* __restrict__ xab,
                                             int E) {
    __shared__ __align__(16) unsigned short Asu[128 * LDAP];
    __shared__ __align__(16) unsigned short Bsu[128 * LDAP];

    const int t = threadIdx.x;

    if (blockIdx.x >= 512) {
        // ---- scatter ----
        const int e = (blockIdx.x - 512) * 256 + t;
        if (e < E) {
            const int s = ei[e];
            const int d = ei[E + e];
            const unsigned int bd = 1u << (d & 31);
            const unsigned int bs = 1u << (s & 31);
            unsigned int o1 = atomicOr(bm + ((size_t)s << 9) + (d >> 5), bd);
            if (!(o1 & bd)) {
                int p = atomicAdd(cnt + s, 1);
                if (p < CAP) list[(size_t)s * CAP + p] = (unsigned short)d;
            }
            unsigned int o2 = atomicOr(bm + ((size_t)d << 9) + (s >> 5), bs);
            if (!(o2 & bs)) {
                int p = atomicAdd(cnt + d, 1);
                if (p < CAP) list[(size_t)d * CAP + p] = (unsigned short)s;
            }
        }
        return;
    }

    // ---- GEMM ----
    const int lane = t & 63;
    const int wid = t >> 6;
    const int wr = wid >> 1, wc = wid & 1;
    const int row0 = (blockIdx.x & 127) * 128;
    const int col0 = (blockIdx.x >> 7) * 128;
    const bool is_upd = (col0 < DD);
    const float* Wsrc = is_upd ? (Wu + (size_t)col0 * DD)
                               : (Wa + (size_t)(col0 - DD) * DD);

    f32x4 acc[4][4] = {};
    bf16x8 av[4], bv[4];

    for (int k0 = 0; k0 < DD; k0 += 32) {
        float4 ga[4], gb[4];
#pragma unroll
        for (int i = 0; i < 4; ++i) {
            const int f = t + 256 * i;       // flat float4 id
            const int r = f >> 3;            // 0..127
            const int cb = f & 7;            // float4 within 32-col panel
            ga[i] = *(const float4*)(x + (size_t)(row0 + r) * DD + k0 + cb * 4);
            gb[i] = *(const float4*)(Wsrc + (size_t)r * DD + k0 + cb * 4);
        }
        __syncthreads();  // previous iter's LDS reads done
#pragma unroll
        for (int i = 0; i < 4; ++i) {
            const int f = t + 256 * i;
            const int r = f >> 3;
            const int cb = f & 7;
            ushort4 ap, bp;
            ap.x = f2bn(ga[i].x); ap.y = f2bn(ga[i].y);
            ap.z = f2bn(ga[i].z); ap.w = f2bn(ga[i].w);
            bp.x = f2bn(gb[i].x); bp.y = f2bn(gb[i].y);
            bp.z = f2bn(gb[i].z); bp.w = f2bn(gb[i].w);
            *(ushort4*)(&Asu[r * LDAP + cb * 4]) = ap;
            *(ushort4*)(&Bsu[r * LDAP + cb * 4]) = bp;
        }
        __syncthreads();
#pragma unroll
        for (int fm = 0; fm < 4; ++fm) {
            uint4 ra = *(const uint4*)(&Asu[(wr * 64 + fm * 16 + (lane & 15)) * LDAP + (lane >> 4) * 8]);
            av[fm] = __builtin_bit_cast(bf16x8, ra);
        }
#pragma unroll
        for (int fn = 0; fn < 4; ++fn) {
            uint4 rb = *(const uint4*)(&Bsu[(wc * 64 + fn * 16 + (lane & 15)) * LDAP + (lane >> 4) * 8]);
            bv[fn] = __builtin_bit_cast(bf16x8, rb);
        }
#pragma unroll
        for (int fm = 0; fm < 4; ++fm)
#pragma unroll
            for (int fn = 0; fn < 4; ++fn)
                acc[fm][fn] = __builtin_amdgcn_mfma_f32_16x16x32_bf16(
                    av[fm], bv[fn], acc[fm][fn], 0, 0, 0);
    }

    // epilogue: C/D layout col = lane&15, row = (lane>>4)*4 + i
    const int gr0 = row0 + wr * 64 + ((lane >> 4) << 2);
    const int gcb = col0 + wc * 64 + (lane & 15);
    if (is_upd) {
#pragma unroll
        for (int fn = 0; fn < 4; ++fn) {
            const int c = gcb + fn * 16;
            const float bias = bu[c] + ba[c];
#pragma unroll
            for (int fm = 0; fm < 4; ++fm) {
                const int r = gr0 + fm * 16;
#pragma unroll
                for (int i = 0; i < 4; ++i)
                    out[(size_t)(r + i) * DD + c] = acc[fm][fn][i] + bias;
            }
        }
    } else {
#pragma unroll
        for (int fn = 0; fn < 4; ++fn) {
            const int c = gcb + fn * 16 - DD;
#pragma unroll
            for (int fm = 0; fm < 4; ++fm) {
                const int r = gr0 + fm * 16;
#pragma unroll
                for (int i = 0; i < 4; ++i)
                    xab[(size_t)(r + i) * DD + c] = f2bn(acc[fm][fn][i]);
            }
        }
    }
}

// ---------------- gather: out[i] += sum_{j in nbr(i)} xab[j] ----------------
// 1 wave per row, 4 rows/block. List comes precomputed from k_mid scatter.
__global__ __launch_bounds__(256) void k_gather(const int* __restrict__ cnt,
                                                const unsigned short* __restrict__ list,
                                                const unsigned short* __restrict__ xab,
                                                float* __restrict__ out) {
    __shared__ unsigned short lds[4][CAP];

    const int t = threadIdx.x;
    const int wid = t >> 6;
    const int lane = t & 63;
    const int row = (blockIdx.x << 2) + wid;

    const int n = min(cnt[row], CAP);
    const unsigned short* gl = list + (size_t)row * CAP;
    for (int i = lane; i < n; i += 64) lds[wid][i] = gl[i];
    // same-wave LDS dep: compiler inserts lgkmcnt wait; no cross-wave sharing.

    const int coff = lane << 2;  // ushort offset: dims 4l..4l+3

    float4 a[8];
#pragma unroll
    for (int j = 0; j < 8; ++j) { a[j].x = 0.f; a[j].y = 0.f; a[j].z = 0.f; a[j].w = 0.f; }

    int i = 0;
    for (; i + 16 <= n; i += 16) {
        ushort4 v[16];
#pragma unroll
        for (int j = 0; j < 16; ++j) {
            const int idx = lds[wid][i + j];
            v[j] = *(const ushort4*)(xab + (((size_t)idx) << 8) + coff);
        }
#pragma unroll
        for (int j = 0; j < 16; ++j) {
            float4& A = a[j & 7];
            A.x += b2f(v[j].x); A.y += b2f(v[j].y);
            A.z += b2f(v[j].z); A.w += b2f(v[j].w);
        }
    }
    for (; i < n; ++i) {
        const int idx = lds[wid][i];
        ushort4 vv = *(const ushort4*)(xab + (((size_t)idx) << 8) + coff);
        a[0].x += b2f(vv.x); a[0].y += b2f(vv.y);
        a[0].z += b2f(vv.z); a[0].w += b2f(vv.w);
    }

#pragma unroll
    for (int j = 4; j < 8; ++j) {
        a[j - 4].x += a[j].x; a[j - 4].y += a[j].y;
        a[j - 4].z += a[j].z; a[j - 4].w += a[j].w;
    }
    a[0].x += a[1].x + a[2].x + a[3].x;
    a[0].y += a[1].y + a[2].y + a[3].y;
    a[0].z += a[1].z + a[2].z + a[3].z;
    a[0].w += a[1].w + a[2].w + a[3].w;

    float4* po = (float4*)(out + (((size_t)row) << 8) + coff);
    float4 o = *po;
    o.x += a[0].x; o.y += a[0].y; o.z += a[0].z; o.w += a[0].w;
    *po = o;
}

extern "C" void kernel_launch(void* const* d_in, const int* in_sizes, int n_in,
                              void* d_out, int out_size, void* d_ws, size_t ws_size,
                              hipStream_t stream) {
    const float* x  = (const float*)d_in[0];
    const int*   ei = (const int*)d_in[1];
    const float* Wu = (const float*)d_in[2];
    const float* bu = (const float*)d_in[3];
    const float* Wa = (const float*)d_in[4];
    const float* ba = (const float*)d_in[5];
    float* out = (float*)d_out;

    const int E = in_sizes[1] / 2;

    char* ws = (char*)d_ws;
    unsigned int* bm = (unsigned int*)ws;                               // 32 MiB
    unsigned short* xab = (unsigned short*)(ws + 33554432);             // 8 MiB
    unsigned short* list = (unsigned short*)(ws + 33554432 + 8388608);  // 7 MiB
    int* cnt = (int*)(ws + 33554432 + 8388608 + (size_t)NN * CAP * 2);  // 64 KiB

    hipMemsetAsync(bm, 0, (size_t)NN * ROW_WORDS * sizeof(unsigned int), stream);
    hipMemsetAsync(cnt, 0, NN * sizeof(int), stream);

    const int scatter_blocks = (E + 255) / 256;
    k_mid<<<512 + scatter_blocks, 256, 0, stream>>>(x, Wu, bu, Wa, ba, ei,
                                                    bm, list, cnt, out, xab, E);
    k_gather<<<NN / 4, 256, 0, stream>>>(cnt, list, xab, out);
}

// Round 5
// 116.213 us; speedup vs baseline: 1.9248x; 1.9248x over previous
//
#include <hip/hip_runtime.h>
#include <hip/hip_fp16.h>

#define NN 16384
#define DD 256
#define ROW_WORDS 512  // NN/32
#define CAP 256        // per-row neighbor list capacity (deg ~ Poisson(64), max ~115)
#define BK 64
#define LDAP 72        // padded LDS row stride in bf16 elems (144 B)

typedef __attribute__((ext_vector_type(8))) __bf16 bf16x8;
typedef __attribute__((ext_vector_type(4))) float f32x4;

__device__ __forceinline__ unsigned short f2bn(float f) {
    __bf16 h = (__bf16)f;  // compiler emits v_cvt_pk_bf16_f32 for pairs
    return __builtin_bit_cast(unsigned short, h);
}

// ---------------- fused: blocks 0..511 GEMM tiles, 512..767 zero the bitmap --------
// GEMM: out = x@Wu^T + bu + ba (col panel 0) ; xab = f16(x@Wa^T) (col panel 1)
// tile 128x128, BK=64, 4 waves (2x2), 4 K-iterations.
__global__ __launch_bounds__(256) void k_gemm_ms(const float* __restrict__ x,
                                                 const float* __restrict__ Wu,
                                                 const float* __restrict__ bu,
                                                 const float* __restrict__ Wa,
                                                 const float* __restrict__ ba,
                                                 float* __restrict__ out,
                                                 __half* __restrict__ xab,
                                                 unsigned int* __restrict__ bm) {
    __shared__ __align__(16) unsigned short Asu[128 * LDAP];
    __shared__ __align__(16) unsigned short Bsu[128 * LDAP];

    const int t = threadIdx.x;

    if (blockIdx.x >= 512) {
        // ---- bitmap memset: 256 blocks x 128 KiB ----
        uint4 z; z.x = 0u; z.y = 0u; z.z = 0u; z.w = 0u;
        uint4* p = (uint4*)bm + (size_t)(blockIdx.x - 512) * 8192;
#pragma unroll 8
        for (int i = t; i < 8192; i += 256) p[i] = z;
        return;
    }

    const int lane = t & 63;
    const int wid = t >> 6;
    const int wr = wid >> 1, wc = wid & 1;
    const int row0 = (blockIdx.x & 127) << 7;
    const int col0 = (blockIdx.x >> 7) << 7;
    const bool is_upd = (col0 < DD);
    const float* Wsrc = is_upd ? (Wu + (size_t)col0 * DD)
                               : (Wa + (size_t)(col0 - DD) * DD);

    f32x4 acc[4][4] = {};

    for (int k0 = 0; k0 < DD; k0 += BK) {
        float4 ga[8], gb[8];
#pragma unroll
        for (int i = 0; i < 8; ++i) {
            const int f = t + 256 * i;   // flat float4 id over 128x64 tile
            const int r = f >> 4;        // 0..127
            const int c4 = f & 15;       // float4 within 64-col panel
            ga[i] = *(const float4*)(x + (size_t)(row0 + r) * DD + k0 + c4 * 4);
            gb[i] = *(const float4*)(Wsrc + (size_t)r * DD + k0 + c4 * 4);
        }
        __syncthreads();  // previous iteration's LDS reads done
#pragma unroll
        for (int i = 0; i < 8; ++i) {
            const int f = t + 256 * i;
            const int r = f >> 4;
            const int c4 = f & 15;
            ushort4 ap, bp;
            ap.x = f2bn(ga[i].x); ap.y = f2bn(ga[i].y);
            ap.z = f2bn(ga[i].z); ap.w = f2bn(ga[i].w);
            bp.x = f2bn(gb[i].x); bp.y = f2bn(gb[i].y);
            bp.z = f2bn(gb[i].z); bp.w = f2bn(gb[i].w);
            *(ushort4*)(&Asu[r * LDAP + c4 * 4]) = ap;
            *(ushort4*)(&Bsu[r * LDAP + c4 * 4]) = bp;
        }
        __syncthreads();
        bf16x8 av[2][4], bv[2][4];
#pragma unroll
        for (int kk = 0; kk < 2; ++kk)
#pragma unroll
            for (int fm = 0; fm < 4; ++fm) {
                uint4 ra = *(const uint4*)(&Asu[(wr * 64 + fm * 16 + (lane & 15)) * LDAP + kk * 32 + (lane >> 4) * 8]);
                av[kk][fm] = __builtin_bit_cast(bf16x8, ra);
                uint4 rb = *(const uint4*)(&Bsu[(wc * 64 + fm * 16 + (lane & 15)) * LDAP + kk * 32 + (lane >> 4) * 8]);
                bv[kk][fm] = __builtin_bit_cast(bf16x8, rb);
            }
#pragma unroll
        for (int kk = 0; kk < 2; ++kk)
#pragma unroll
            for (int fm = 0; fm < 4; ++fm)
#pragma unroll
                for (int fn = 0; fn < 4; ++fn)
                    acc[fm][fn] = __builtin_amdgcn_mfma_f32_16x16x32_bf16(
                        av[kk][fm], bv[kk][fn], acc[fm][fn], 0, 0, 0);
    }

    // epilogue: C/D layout col = lane&15, row = (lane>>4)*4 + i
    const int gr0 = row0 + wr * 64 + ((lane >> 4) << 2);
    const int gcb = col0 + wc * 64 + (lane & 15);
    if (is_upd) {
#pragma unroll
        for (int fn = 0; fn < 4; ++fn) {
            const int c = gcb + fn * 16;
            const float bias = bu[c] + ba[c];
#pragma unroll
            for (int fm = 0; fm < 4; ++fm) {
                const int r = gr0 + fm * 16;
#pragma unroll
                for (int i = 0; i < 4; ++i)
                    out[(size_t)(r + i) * DD + c] = acc[fm][fn][i] + bias;
            }
        }
    } else {
#pragma unroll
        for (int fn = 0; fn < 4; ++fn) {
            const int c = gcb + fn * 16 - DD;
#pragma unroll
            for (int fm = 0; fm < 4; ++fm) {
                const int r = gr0 + fm * 16;
#pragma unroll
                for (int i = 0; i < 4; ++i)
                    xab[(size_t)(r + i) * DD + c] = __float2half(acc[fm][fn][i]);
            }
        }
    }
}

// ---------------- scatter edges into symmetric bitmap (SET semantics) ----------------
__global__ __launch_bounds__(256) void k_scatter(const int* __restrict__ ei,
                                                 unsigned int* __restrict__ bm,
                                                 int E) {
    int e = blockIdx.x * 256 + threadIdx.x;
    if (e >= E) return;
    int s = ei[e];
    int d = ei[E + e];
    atomicOr(bm + ((size_t)s << 9) + (d >> 5), 1u << (d & 31));
    atomicOr(bm + ((size_t)d << 9) + (s >> 5), 1u << (s & 31));
}

// ---------------- gather: out[i] += sum_{j in nbr(i)} xab[j] (f16 packed adds) ------
// 1 wave per row, 4 rows/block. Extraction: popcount + wave prefix scan (no atomics).
__global__ __launch_bounds__(256) void k_gather(const unsigned int* __restrict__ bm,
                                                const __half* __restrict__ xab,
                                                float* __restrict__ out) {
    __shared__ unsigned short list[4][CAP];

    const int t = threadIdx.x;
    const int wid = t >> 6;
    const int lane = t & 63;
    const int row = (blockIdx.x << 2) + wid;

    const uint4* rbm = (const uint4*)(bm + ((size_t)row << 9));
    int base = 0;
#pragma unroll
    for (int g = 0; g < 2; ++g) {
        const int q = (g << 6) + lane;           // uint4 index (coalesced)
        uint4 w = rbm[q];
        int c = __popc(w.x) + __popc(w.y) + __popc(w.z) + __popc(w.w);
        int incl = c;
#pragma unroll
        for (int d = 1; d < 64; d <<= 1) {
            int y = __shfl_up(incl, d, 64);
            if (lane >= d) incl += y;
        }
        int pos = base + incl - c;               // exclusive slot
        const int wbase = q << 7;                // q * 128 bits
        unsigned int b; int bit;
        b = w.x; while (b) { bit = __ffs(b) - 1; b &= b - 1;
            if (pos < CAP) list[wid][pos] = (unsigned short)(wbase + bit); ++pos; }
        b = w.y; while (b) { bit = __ffs(b) - 1; b &= b - 1;
            if (pos < CAP) list[wid][pos] = (unsigned short)(wbase + 32 + bit); ++pos; }
        b = w.z; while (b) { bit = __ffs(b) - 1; b &= b - 1;
            if (pos < CAP) list[wid][pos] = (unsigned short)(wbase + 64 + bit); ++pos; }
        b = w.w; while (b) { bit = __ffs(b) - 1; b &= b - 1;
            if (pos < CAP) list[wid][pos] = (unsigned short)(wbase + 96 + bit); ++pos; }
        base += __shfl(incl, 63, 64);            // pass total (wave-uniform)
    }
    __syncthreads();  // list visible across lanes

    const int n = min(base, CAP);
    const int coff = lane << 2;  // f16 dims 4l..4l+3

    __half2 a0[8], a1[8];
    const __half2 z2 = __float2half2_rn(0.0f);
#pragma unroll
    for (int j = 0; j < 8; ++j) { a0[j] = z2; a1[j] = z2; }

    int i = 0;
    for (; i + 8 <= n; i += 8) {
        uint2 v[8];
#pragma unroll
        for (int j = 0; j < 8; ++j) {
            const int idx = list[wid][i + j];
            v[j] = *(const uint2*)(xab + (((size_t)idx) << 8) + coff);
        }
#pragma unroll
        for (int j = 0; j < 8; ++j) {
            a0[j] = __hadd2(a0[j], __builtin_bit_cast(__half2, v[j].x));
            a1[j] = __hadd2(a1[j], __builtin_bit_cast(__half2, v[j].y));
        }
    }
    for (; i < n; ++i) {
        const int idx = list[wid][i];
        uint2 v = *(const uint2*)(xab + (((size_t)idx) << 8) + coff);
        a0[0] = __hadd2(a0[0], __builtin_bit_cast(__half2, v.x));
        a1[0] = __hadd2(a1[0], __builtin_bit_cast(__half2, v.y));
    }

#pragma unroll
    for (int j = 1; j < 8; ++j) { a0[0] = __hadd2(a0[0], a0[j]); a1[0] = __hadd2(a1[0], a1[j]); }
    const float2 f0 = __half22float2(a0[0]);
    const float2 f1 = __half22float2(a1[0]);

    float4* po = (float4*)(out + (((size_t)row) << 8) + coff);
    float4 o = *po;
    o.x += f0.x; o.y += f0.y; o.z += f1.x; o.w += f1.y;
    *po = o;
}

extern "C" void kernel_launch(void* const* d_in, const int* in_sizes, int n_in,
                              void* d_out, int out_size, void* d_ws, size_t ws_size,
                              hipStream_t stream) {
    const float* x  = (const float*)d_in[0];
    const int*   ei = (const int*)d_in[1];
    const float* Wu = (const float*)d_in[2];
    const float* bu = (const float*)d_in[3];
    const float* Wa = (const float*)d_in[4];
    const float* ba = (const float*)d_in[5];
    float* out = (float*)d_out;

    const int E = in_sizes[1] / 2;

    char* ws = (char*)d_ws;
    unsigned int* bm = (unsigned int*)ws;                 // 32 MiB bitmap
    __half* xab = (__half*)(ws + 33554432);               // 8 MiB f16 xa

    // k1: GEMM (512 blocks) + bitmap zeroing (256 blocks) fused
    k_gemm_ms<<<768, 256, 0, stream>>>(x, Wu, bu, Wa, ba, out, xab, bm);
    // k2: edge scatter (needs zeroed bitmap)
    k_scatter<<<(E + 255) / 256, 256, 0, stream>>>(ei, bm, E);
    // k3: gather (needs bitmap + xab)
    k_gather<<<NN / 4, 256, 0, stream>>>(bm, xab, out);
}